// Round 1
// baseline (1658.618 us; speedup 1.0000x reference)
//
#include <hip/hip_runtime.h>
#include <math.h>

#define WAVE 64
#define NC 21

__device__ __forceinline__ unsigned int f32_ord(float f) {
    unsigned int u = __float_as_uint(f);
    return (u & 0x80000000u) ? ~u : (u | 0x80000000u);
}

__device__ __forceinline__ unsigned long long wave_min_u64(unsigned long long v) {
#pragma unroll
    for (int off = 32; off >= 1; off >>= 1) {
        unsigned long long o = __shfl_xor(v, off, WAVE);
        v = (o < v) ? o : v;
    }
    return v;
}

__device__ __forceinline__ float wave_max_f32(float v) {
#pragma unroll
    for (int off = 32; off >= 1; off >>= 1)
        v = fmaxf(v, __shfl_xor(v, off, WAVE));
    return v;
}

__device__ __forceinline__ float wave_sum_f32(float v) {
#pragma unroll
    for (int off = 32; off >= 1; off >>= 1)
        v += __shfl_xor(v, off, WAVE);
    return v;
}

// ---------------------------------------------------------------------------
// Kernel A: for each query point in level i (i>0), find K nearest points in
// coord0 (4096 pts), count their labels, write argmax label (lowest-class tie).
// One wave (64 threads) per query.
// ---------------------------------------------------------------------------
template <int K>
__global__ __launch_bounds__(64) void knn_label_kernel(
    const float* __restrict__ qc, int NQ,
    const float* __restrict__ rc,      // [B,4096,3]
    const int* __restrict__ rl,        // [B,4096]
    int* __restrict__ out)             // [B,NQ]
{
    __shared__ float dist[4096];
    __shared__ int sel_lbl[K];
    int blk = blockIdx.x;
    int b = blk / NQ, qi = blk - b * NQ;
    int lane = threadIdx.x;

    const float* qp = qc + ((long)b * NQ + qi) * 3;
    float qx = qp[0], qy = qp[1], qz = qp[2];
    float nq = qx * qx + qy * qy + qz * qz;

    const float* rp = rc + (long)b * 4096 * 3;
    for (int t = lane; t < 4096; t += 64) {
        float rx = rp[3 * t], ry = rp[3 * t + 1], rz = rp[3 * t + 2];
        float nr = rx * rx + ry * ry + rz * rz;
        float dot = qx * rx + qy * ry + qz * rz;
        dist[t] = -2.0f * dot + nq + nr;   // ((-2*dot)+nq)+nr like reference
    }
    __syncthreads();

    for (int k = 0; k < K; ++k) {
        unsigned long long best = ~0ull;
        for (int t = lane; t < 4096; t += 64) {
            unsigned long long key =
                ((unsigned long long)f32_ord(dist[t]) << 32) | (unsigned)t;
            best = (key < best) ? key : best;
        }
        best = wave_min_u64(best);
        int s = (int)(unsigned)best;
        if (lane == 0) {
            dist[s] = INFINITY;
            sel_lbl[k] = rl[(long)b * 4096 + s];
        }
        __syncthreads();
    }

    // count labels among K neighbors; argmax with lowest-class tie-break
    int key = 0;
    if (lane < NC) {
        int cnt = 0;
#pragma unroll
        for (int k = 0; k < K; ++k) cnt += (sel_lbl[k] == lane) ? 1 : 0;
        key = (cnt << 8) | (255 - lane);
    }
#pragma unroll
    for (int off = 32; off >= 1; off >>= 1) {
        int o = __shfl_xor(key, off, WAVE);
        key = (o > key) ? o : key;
    }
    if (lane == 0) out[(long)b * NQ + qi] = 255 - (key & 255);
}

// ---------------------------------------------------------------------------
// Kernel B: per level — KNN within the level (NS nearest of NI), then the
// masked feature-softmax accumulation. One wave per query point.
// ---------------------------------------------------------------------------
template <int NI, int NS>
__global__ __launch_bounds__(64) void boundary_kernel(
    const float* __restrict__ coord,   // [B,NI,3]
    const float* __restrict__ feat,    // [B,NI,32]
    const int* __restrict__ lbl,       // [B,NI]
    double* __restrict__ pos,
    double* __restrict__ neg,
    int* __restrict__ anyf)
{
    __shared__ float dist[NI];
    __shared__ int sel[NS];
    int blk = blockIdx.x;
    int b = blk / NI, qi = blk - b * NI;
    int lane = threadIdx.x;

    const float* qp = coord + ((long)b * NI + qi) * 3;
    float qx = qp[0], qy = qp[1], qz = qp[2];
    float nq = qx * qx + qy * qy + qz * qz;

    const float* rp = coord + (long)b * NI * 3;
    for (int t = lane; t < NI; t += 64) {
        float rx = rp[3 * t], ry = rp[3 * t + 1], rz = rp[3 * t + 2];
        float nr = rx * rx + ry * ry + rz * rz;
        float dot = qx * rx + qy * ry + qz * rz;
        dist[t] = -2.0f * dot + nq + nr;
    }
    __syncthreads();

    for (int k = 0; k < NS; ++k) {
        unsigned long long best = ~0ull;
        for (int t = lane; t < NI; t += 64) {
            unsigned long long key =
                ((unsigned long long)f32_ord(dist[t]) << 32) | (unsigned)t;
            best = (key < best) ? key : best;
        }
        best = wave_min_u64(best);
        int s = (int)(unsigned)best;
        if (lane == 0) { dist[s] = INFINITY; sel[k] = s; }
        __syncthreads();
    }

    int center = lbl[(long)b * NI + qi];
    bool m = false;
    float dj = -INFINITY;
    if (lane < NS) {
        int nb = sel[lane];
        m = (lbl[(long)b * NI + nb] == center);
        const float* fq = feat + ((long)b * NI + qi) * 32;
        const float* fn = feat + ((long)b * NI + nb) * 32;
        float s = 0.f;
#pragma unroll
        for (int d = 0; d < 32; ++d) {
            float df = fq[d] - fn[d];
            s += df * df;
        }
        dj = -sqrtf(s + 1e-6f);
    }
    unsigned long long mb = __ballot(m);
    int cnt = __popcll(mb);
    float mx = wave_max_f32(dj);        // lanes >= NS hold -inf
    float ej = 0.f, pj = 0.f;
    if (lane < NS) {
        ej = expf(dj - mx);             // TEMPERATURE == 1
        pj = m ? ej : 0.f;
    }
    float se = wave_sum_f32(ej);
    float sp = wave_sum_f32(pj);
    bool pm = (cnt > 0) && (cnt < NS);
    if (pm && lane == 0) {
        atomicAdd(pos, (double)sp);
        atomicAdd(neg, (double)se);
        *anyf = 1;
    }
}

__global__ void init_kernel(double* pos, double* neg, int* anyf) {
    int t = threadIdx.x;
    if (t < 5) { pos[t] = 0.0; neg[t] = 0.0; anyf[t] = 0; }
}

__global__ void finalize_kernel(const double* pos, const double* neg,
                                const int* anyf, float* out) {
    if (threadIdx.x == 0 && blockIdx.x == 0) {
        float loss = 0.f;
        for (int i = 0; i < 5; ++i) {
            if (anyf[i]) {
                float p = (float)pos[i];
                float n = (float)neg[i];
                loss += -logf(p / (n + 1e-6f));
            }
        }
        out[0] = loss;
    }
}

extern "C" void kernel_launch(void* const* d_in, const int* in_sizes, int n_in,
                              void* d_out, int out_size, void* d_ws, size_t ws_size,
                              hipStream_t stream) {
    (void)out_size; (void)ws_size;
    const int* labels = (const int*)d_in[0];
    const float* coord[5];
    const float* feat[5];
    // setup_inputs dict order is interleaved: labels, c0,f0, c1,f1, ... ; be
    // robust to the grouped (signature) order too.
    bool interleaved = (n_in >= 3 && in_sizes[2] == 2 * 4096 * 32);
    if (interleaved) {
        for (int i = 0; i < 5; ++i) {
            coord[i] = (const float*)d_in[1 + 2 * i];
            feat[i]  = (const float*)d_in[2 + 2 * i];
        }
    } else {
        for (int i = 0; i < 5; ++i) {
            coord[i] = (const float*)d_in[1 + i];
            feat[i]  = (const float*)d_in[6 + i];
        }
    }
    int B = in_sizes[0] / 4096;   // = 2

    double* posA = (double*)d_ws;            // 5 doubles
    double* negA = posA + 5;                 // 5 doubles
    int* anyA = (int*)(negA + 5);            // 5 ints (+3 pad)
    int* lbl1 = anyA + 8;
    int* lbl2 = lbl1 + B * 1024;
    int* lbl3 = lbl2 + B * 256;
    int* lbl4 = lbl3 + B * 64;

    hipLaunchKernelGGL(init_kernel, dim3(1), dim3(64), 0, stream, posA, negA, anyA);

    hipLaunchKernelGGL((knn_label_kernel<4>),  dim3(B * 1024), dim3(64), 0, stream,
                       coord[1], 1024, coord[0], labels, lbl1);
    hipLaunchKernelGGL((knn_label_kernel<8>),  dim3(B * 256),  dim3(64), 0, stream,
                       coord[2], 256,  coord[0], labels, lbl2);
    hipLaunchKernelGGL((knn_label_kernel<12>), dim3(B * 64),   dim3(64), 0, stream,
                       coord[3], 64,   coord[0], labels, lbl3);
    hipLaunchKernelGGL((knn_label_kernel<16>), dim3(B * 16),   dim3(64), 0, stream,
                       coord[4], 16,   coord[0], labels, lbl4);

    hipLaunchKernelGGL((boundary_kernel<4096, 64>), dim3(B * 4096), dim3(64), 0, stream,
                       coord[0], feat[0], labels, posA + 0, negA + 0, anyA + 0);
    hipLaunchKernelGGL((boundary_kernel<1024, 32>), dim3(B * 1024), dim3(64), 0, stream,
                       coord[1], feat[1], lbl1, posA + 1, negA + 1, anyA + 1);
    hipLaunchKernelGGL((boundary_kernel<256, 16>),  dim3(B * 256),  dim3(64), 0, stream,
                       coord[2], feat[2], lbl2, posA + 2, negA + 2, anyA + 2);
    hipLaunchKernelGGL((boundary_kernel<64, 8>),    dim3(B * 64),   dim3(64), 0, stream,
                       coord[3], feat[3], lbl3, posA + 3, negA + 3, anyA + 3);
    hipLaunchKernelGGL((boundary_kernel<16, 4>),    dim3(B * 16),   dim3(64), 0, stream,
                       coord[4], feat[4], lbl4, posA + 4, negA + 4, anyA + 4);

    hipLaunchKernelGGL(finalize_kernel, dim3(1), dim3(1), 0, stream,
                       posA, negA, anyA, (float*)d_out);
}

// Round 2
// 684.469 us; speedup vs baseline: 2.4232x; 2.4232x over previous
//
#include <hip/hip_runtime.h>
#include <math.h>

#define WAVE 64
#define NC 21

__device__ __forceinline__ unsigned int f32_ord(float f) {
    unsigned int u = __float_as_uint(f);
    return (u & 0x80000000u) ? ~u : (u | 0x80000000u);
}

__device__ __forceinline__ unsigned long long wave_min_u64(unsigned long long v) {
#pragma unroll
    for (int off = 32; off >= 1; off >>= 1) {
        unsigned long long o = __shfl_xor(v, off, WAVE);
        v = (o < v) ? o : v;
    }
    return v;
}

__device__ __forceinline__ float wave_max_f32(float v) {
#pragma unroll
    for (int off = 32; off >= 1; off >>= 1)
        v = fmaxf(v, __shfl_xor(v, off, WAVE));
    return v;
}

__device__ __forceinline__ float wave_sum_f32(float v) {
#pragma unroll
    for (int off = 32; off >= 1; off >>= 1)
        v += __shfl_xor(v, off, WAVE);
    return v;
}

// Register-resident exact top-NS selection.
// Each lane owns NPL candidates: global idx g = j*64 + lane, key ok[j] (ordered
// f32 bits; 0xFFFFFFFF = invalid/consumed). Returns this lane's k==lane
// selection (global index) — lane k holds the k-th nearest. Tie-break is
// exact lower-global-index-first (matches jax.lax.top_k).
template <int NPL, int NS>
__device__ __forceinline__ int select_knn(unsigned int (&ok)[NPL], int lane) {
    unsigned long long used = 0ull;
    int my_sel = 0;
#pragma unroll 1
    for (int k = 0; k < NS; ++k) {
        unsigned int best = 0xFFFFFFFFu;
        int bestj = 0;
#pragma unroll
        for (int j = 0; j < NPL; ++j) {
            unsigned int v = (used & (1ull << j)) ? 0xFFFFFFFFu : ok[j];
            bool lt = v < best;           // strict: keeps smallest j (= smallest g) on ties
            best = lt ? v : best;
            bestj = lt ? j : bestj;       // j is an inline const in unrolled code
        }
        unsigned long long key =
            ((unsigned long long)best << 32) | (unsigned)(bestj * 64 + lane);
        key = wave_min_u64(key);
        int g = (int)(unsigned)key;
        if ((g & 63) == lane) used |= 1ull << (g >> 6);
        if (k == lane) my_sel = g;
    }
    return my_sel;
}

// ---------------------------------------------------------------------------
// Kernel A (register version): for each query in level i (i>0), find K nearest
// in coord0 (4096 pts), argmax of neighbor-label counts (lowest class on tie).
// One wave per query, no LDS.
// ---------------------------------------------------------------------------
template <int K>
__global__ __launch_bounds__(64, 4) void knn_label_kernel(
    const float* __restrict__ qc, int NQ,
    const float* __restrict__ rc,      // [B,4096,3]
    const int* __restrict__ rl,        // [B,4096]
    int* __restrict__ out)             // [B,NQ]
{
    int blk = blockIdx.x;
    int b = blk / NQ, qi = blk - b * NQ;
    int lane = threadIdx.x;

    const float* qp = qc + ((long)b * NQ + qi) * 3;
    float qx = qp[0], qy = qp[1], qz = qp[2];
    float nq = qx * qx + qy * qy + qz * qz;

    const float* rp = rc + (long)b * 4096 * 3;
    unsigned int ok[64];
#pragma unroll
    for (int j = 0; j < 64; ++j) {
        int g = j * 64 + lane;
        float rx = rp[3 * g], ry = rp[3 * g + 1], rz = rp[3 * g + 2];
        float nr = rx * rx + ry * ry + rz * rz;
        float dot = qx * rx + qy * ry + qz * rz;
        float d = -2.0f * dot + nq + nr;   // identical expression to validated R1
        ok[j] = f32_ord(d);
    }

    int my_sel = select_knn<64, K>(ok, lane);

    int lb = -1;
    if (lane < K) lb = rl[(long)b * 4096 + my_sel];

    int cnt = 0;
#pragma unroll
    for (int k = 0; k < K; ++k) {
        int lk = __shfl(lb, k, WAVE);
        cnt += (lk == lane) ? 1 : 0;
    }
    int key = (lane < NC) ? ((cnt << 8) | (255 - lane)) : 0;
#pragma unroll
    for (int off = 32; off >= 1; off >>= 1) {
        int o = __shfl_xor(key, off, WAVE);
        key = (o > key) ? o : key;
    }
    if (lane == 0) out[(long)b * NQ + qi] = 255 - (key & 255);
}

// ---------------------------------------------------------------------------
// Kernel B (register version): per level — KNN within the level (NS of NI),
// masked feature-softmax accumulation. One wave per query, no LDS.
// ---------------------------------------------------------------------------
template <int NI, int NS>
__global__ __launch_bounds__(64, 4) void boundary_kernel(
    const float* __restrict__ coord,   // [B,NI,3]
    const float* __restrict__ feat,    // [B,NI,32]
    const int* __restrict__ lbl,       // [B,NI]
    double* __restrict__ pos,
    double* __restrict__ neg,
    int* __restrict__ anyf)
{
    constexpr int NPL = (NI >= 64) ? NI / 64 : 1;
    int blk = blockIdx.x;
    int b = blk / NI, qi = blk - b * NI;
    int lane = threadIdx.x;

    const float* qp = coord + ((long)b * NI + qi) * 3;
    float qx = qp[0], qy = qp[1], qz = qp[2];
    float nq = qx * qx + qy * qy + qz * qz;

    const float* rp = coord + (long)b * NI * 3;
    unsigned int ok[NPL];
#pragma unroll
    for (int j = 0; j < NPL; ++j) {
        int g = j * 64 + lane;
        unsigned int o = 0xFFFFFFFFu;
        if (NI >= 64 || g < NI) {
            float rx = rp[3 * g], ry = rp[3 * g + 1], rz = rp[3 * g + 2];
            float nr = rx * rx + ry * ry + rz * rz;
            float dot = qx * rx + qy * ry + qz * rz;
            float d = -2.0f * dot + nq + nr;
            o = f32_ord(d);
        }
        ok[j] = o;
    }

    int my_sel = select_knn<NPL, NS>(ok, lane);

    int center = lbl[(long)b * NI + qi];
    bool m = false;
    float dj = -INFINITY;
    if (lane < NS) {
        int nb = my_sel;
        m = (lbl[(long)b * NI + nb] == center);
        const float* fq = feat + ((long)b * NI + qi) * 32;
        const float* fn = feat + ((long)b * NI + nb) * 32;
        float s = 0.f;
#pragma unroll
        for (int d = 0; d < 32; ++d) {
            float df = fq[d] - fn[d];
            s += df * df;
        }
        dj = -sqrtf(s + 1e-6f);
    }
    unsigned long long mb = __ballot(m);
    int cnt = __popcll(mb);
    float mx = wave_max_f32(dj);        // lanes >= NS hold -inf
    float ej = 0.f, pj = 0.f;
    if (lane < NS) {
        ej = expf(dj - mx);             // TEMPERATURE == 1
        pj = m ? ej : 0.f;
    }
    float se = wave_sum_f32(ej);
    float sp = wave_sum_f32(pj);
    bool pm = (cnt > 0) && (cnt < NS);
    if (pm && lane == 0) {
        atomicAdd(pos, (double)sp);
        atomicAdd(neg, (double)se);
        *anyf = 1;
    }
}

__global__ void init_kernel(double* pos, double* neg, int* anyf) {
    int t = threadIdx.x;
    if (t < 5) { pos[t] = 0.0; neg[t] = 0.0; anyf[t] = 0; }
}

__global__ void finalize_kernel(const double* pos, const double* neg,
                                const int* anyf, float* out) {
    if (threadIdx.x == 0 && blockIdx.x == 0) {
        float loss = 0.f;
        for (int i = 0; i < 5; ++i) {
            if (anyf[i]) {
                float p = (float)pos[i];
                float n = (float)neg[i];
                loss += -logf(p / (n + 1e-6f));
            }
        }
        out[0] = loss;
    }
}

extern "C" void kernel_launch(void* const* d_in, const int* in_sizes, int n_in,
                              void* d_out, int out_size, void* d_ws, size_t ws_size,
                              hipStream_t stream) {
    (void)out_size; (void)ws_size;
    const int* labels = (const int*)d_in[0];
    const float* coord[5];
    const float* feat[5];
    bool interleaved = (n_in >= 3 && in_sizes[2] == 2 * 4096 * 32);
    if (interleaved) {
        for (int i = 0; i < 5; ++i) {
            coord[i] = (const float*)d_in[1 + 2 * i];
            feat[i]  = (const float*)d_in[2 + 2 * i];
        }
    } else {
        for (int i = 0; i < 5; ++i) {
            coord[i] = (const float*)d_in[1 + i];
            feat[i]  = (const float*)d_in[6 + i];
        }
    }
    int B = in_sizes[0] / 4096;   // = 2

    double* posA = (double*)d_ws;            // 5 doubles
    double* negA = posA + 5;                 // 5 doubles
    int* anyA = (int*)(negA + 5);            // 5 ints (+3 pad)
    int* lbl1 = anyA + 8;
    int* lbl2 = lbl1 + B * 1024;
    int* lbl3 = lbl2 + B * 256;
    int* lbl4 = lbl3 + B * 64;

    hipLaunchKernelGGL(init_kernel, dim3(1), dim3(64), 0, stream, posA, negA, anyA);

    hipLaunchKernelGGL((knn_label_kernel<4>),  dim3(B * 1024), dim3(64), 0, stream,
                       coord[1], 1024, coord[0], labels, lbl1);
    hipLaunchKernelGGL((knn_label_kernel<8>),  dim3(B * 256),  dim3(64), 0, stream,
                       coord[2], 256,  coord[0], labels, lbl2);
    hipLaunchKernelGGL((knn_label_kernel<12>), dim3(B * 64),   dim3(64), 0, stream,
                       coord[3], 64,   coord[0], labels, lbl3);
    hipLaunchKernelGGL((knn_label_kernel<16>), dim3(B * 16),   dim3(64), 0, stream,
                       coord[4], 16,   coord[0], labels, lbl4);

    hipLaunchKernelGGL((boundary_kernel<4096, 64>), dim3(B * 4096), dim3(64), 0, stream,
                       coord[0], feat[0], labels, posA + 0, negA + 0, anyA + 0);
    hipLaunchKernelGGL((boundary_kernel<1024, 32>), dim3(B * 1024), dim3(64), 0, stream,
                       coord[1], feat[1], lbl1, posA + 1, negA + 1, anyA + 1);
    hipLaunchKernelGGL((boundary_kernel<256, 16>),  dim3(B * 256),  dim3(64), 0, stream,
                       coord[2], feat[2], lbl2, posA + 2, negA + 2, anyA + 2);
    hipLaunchKernelGGL((boundary_kernel<64, 8>),    dim3(B * 64),   dim3(64), 0, stream,
                       coord[3], feat[3], lbl3, posA + 3, negA + 3, anyA + 3);
    hipLaunchKernelGGL((boundary_kernel<16, 4>),    dim3(B * 16),   dim3(64), 0, stream,
                       coord[4], feat[4], lbl4, posA + 4, negA + 4, anyA + 4);

    hipLaunchKernelGGL(finalize_kernel, dim3(1), dim3(1), 0, stream,
                       posA, negA, anyA, (float*)d_out);
}

// Round 3
// 620.805 us; speedup vs baseline: 2.6717x; 1.1025x over previous
//
#include <hip/hip_runtime.h>
#include <math.h>

#define WAVE 64
#define NC 21

__device__ __forceinline__ unsigned int f32_ord(float f) {
    unsigned int u = __float_as_uint(f);
    return (u & 0x80000000u) ? ~u : (u | 0x80000000u);
}

__device__ __forceinline__ unsigned wave_min_u32(unsigned v) {
#pragma unroll
    for (int off = 32; off >= 1; off >>= 1) {
        unsigned o = __shfl_xor(v, off, WAVE);
        v = (o < v) ? o : v;
    }
    return v;
}

__device__ __forceinline__ int wave_sum_i32(int v) {
#pragma unroll
    for (int off = 32; off >= 1; off >>= 1)
        v += __shfl_xor(v, off, WAVE);
    return v;
}

__device__ __forceinline__ float wave_max_f32(float v) {
#pragma unroll
    for (int off = 32; off >= 1; off >>= 1)
        v = fmaxf(v, __shfl_xor(v, off, WAVE));
    return v;
}

__device__ __forceinline__ float wave_sum_f32(float v) {
#pragma unroll
    for (int off = 32; off >= 1; off >>= 1)
        v += __shfl_xor(v, off, WAVE);
    return v;
}

// ---------------------------------------------------------------------------
// Exact top-NS *set* selection via binary-search threshold on ordered-f32 keys.
// Each lane owns NPL candidates (global idx g = j*64+lane, key ok[j];
// 0xFFFFFFFF = invalid). Writes the NS selected global indices to sel[] (LDS,
// arbitrary order). Tie-break identical to jax.lax.top_k (lower g first).
// ---------------------------------------------------------------------------
template <int NPL, int NS>
__device__ __forceinline__ void select_knn_set(const unsigned (&ok)[NPL],
                                               int lane, int* sel) {
    // V = min{v : count(<= v) >= NS}
    unsigned lo = 0u, hi = 0xFFFFFFFFu;
    while (lo < hi) {
        unsigned piv = lo + ((hi - lo) >> 1);
        int c = 0;
#pragma unroll
        for (int j = 0; j < NPL; ++j) c += (ok[j] <= piv) ? 1 : 0;
        c = wave_sum_i32(c);                 // uniform
        if (c >= NS) hi = piv; else lo = piv + 1;
    }
    unsigned V = lo;

    int clt = 0;
#pragma unroll
    for (int j = 0; j < NPL; ++j) clt += (ok[j] < V) ? 1 : 0;
    clt = wave_sum_i32(clt);                 // uniform, < NS
    int R = NS - clt;                        // >= 1

    // compact all strictly-below-threshold candidates (ballot prefix, no atomics)
    int base = 0;
#pragma unroll
    for (int j = 0; j < NPL; ++j) {
        bool s = ok[j] < V;
        unsigned long long mk = __ballot(s);
        if (s) {
            int off = base + __popcll(mk & ((1ull << lane) - 1ull));
            sel[off] = j * 64 + lane;
        }
        base += __popcll(mk);
    }

    // ties at V: take R smallest global indices among ok[j] == V
    unsigned long long consumed = 0ull;
    for (int r = 0; r < R; ++r) {
        int bj = NPL;                        // smallest unconsumed j with ok[j]==V
#pragma unroll
        for (int j = NPL - 1; j >= 0; --j)
            if (ok[j] == V && !((consumed >> j) & 1ull)) bj = j;
        unsigned g = (bj < NPL) ? (unsigned)(bj * 64 + lane) : 0xFFFFFFFFu;
        unsigned mg = wave_min_u32(g);
        if (g == mg && bj < NPL) {           // unique winner lane
            consumed |= 1ull << bj;
            sel[clt + r] = (int)mg;
        }
    }
    __syncthreads();
}

// ---------------------------------------------------------------------------
// Kernel A: for each query in level i (i>0), K nearest in coord0 (4096 pts),
// argmax of neighbor-label counts (lowest class on tie). One wave per query.
// ---------------------------------------------------------------------------
template <int K>
__global__
__attribute__((amdgpu_flat_work_group_size(64, 64), amdgpu_waves_per_eu(4, 4)))
void knn_label_kernel(
    const float* __restrict__ qc, int NQ,
    const float* __restrict__ rc,      // [B,4096,3]
    const int* __restrict__ rl,        // [B,4096]
    int* __restrict__ out)             // [B,NQ]
{
    __shared__ int sel[K];
    int blk = blockIdx.x;
    int b = blk / NQ, qi = blk - b * NQ;
    int lane = threadIdx.x;

    const float* qp = qc + ((long)b * NQ + qi) * 3;
    float qx = qp[0], qy = qp[1], qz = qp[2];
    float nq = qx * qx + qy * qy + qz * qz;

    const float* rp = rc + (long)b * 4096 * 3;
    unsigned ok[64];
#pragma unroll
    for (int j = 0; j < 64; ++j) {
        int g = j * 64 + lane;
        float rx = rp[3 * g], ry = rp[3 * g + 1], rz = rp[3 * g + 2];
        float nr = rx * rx + ry * ry + rz * rz;
        float dot = qx * rx + qy * ry + qz * rz;
        float d = -2.0f * dot + nq + nr;   // identical expression to validated R1/R2
        ok[j] = f32_ord(d);
    }

    select_knn_set<64, K>(ok, lane, sel);

    int lb = -1;
    if (lane < K) lb = rl[(long)b * 4096 + sel[lane]];

    int cnt = 0;
#pragma unroll
    for (int k = 0; k < K; ++k) {
        int lk = __shfl(lb, k, WAVE);
        cnt += (lk == lane) ? 1 : 0;
    }
    int key = (lane < NC) ? ((cnt << 8) | (255 - lane)) : 0;
#pragma unroll
    for (int off = 32; off >= 1; off >>= 1) {
        int o = __shfl_xor(key, off, WAVE);
        key = (o > key) ? o : key;
    }
    if (lane == 0) out[(long)b * NQ + qi] = 255 - (key & 255);
}

// ---------------------------------------------------------------------------
// Kernel B: per level — KNN set within the level (NS of NI), masked
// feature-softmax accumulation. One wave per query.
// ---------------------------------------------------------------------------
template <int NI, int NS>
__global__
__attribute__((amdgpu_flat_work_group_size(64, 64), amdgpu_waves_per_eu(4, 4)))
void boundary_kernel(
    const float* __restrict__ coord,   // [B,NI,3]
    const float* __restrict__ feat,    // [B,NI,32]
    const int* __restrict__ lbl,       // [B,NI]
    double* __restrict__ pos,
    double* __restrict__ neg,
    int* __restrict__ anyf)
{
    constexpr int NPL = (NI + 63) / 64;
    __shared__ int sel[NS];
    int blk = blockIdx.x;
    int b = blk / NI, qi = blk - b * NI;
    int lane = threadIdx.x;

    const float* qp = coord + ((long)b * NI + qi) * 3;
    float qx = qp[0], qy = qp[1], qz = qp[2];
    float nq = qx * qx + qy * qy + qz * qz;

    const float* rp = coord + (long)b * NI * 3;
    unsigned ok[NPL];
#pragma unroll
    for (int j = 0; j < NPL; ++j) {
        int g = j * 64 + lane;
        unsigned o = 0xFFFFFFFFu;
        if (NI >= 64 || g < NI) {
            float rx = rp[3 * g], ry = rp[3 * g + 1], rz = rp[3 * g + 2];
            float nr = rx * rx + ry * ry + rz * rz;
            float dot = qx * rx + qy * ry + qz * rz;
            float d = -2.0f * dot + nq + nr;
            o = f32_ord(d);
        }
        ok[j] = o;
    }

    select_knn_set<NPL, NS>(ok, lane, sel);

    int center = lbl[(long)b * NI + qi];
    bool m = false;
    float dj = -INFINITY;
    if (lane < NS) {
        int nb = sel[lane];
        m = (lbl[(long)b * NI + nb] == center);
        const float* fq = feat + ((long)b * NI + qi) * 32;
        const float* fn = feat + ((long)b * NI + nb) * 32;
        float s = 0.f;
#pragma unroll
        for (int d = 0; d < 32; ++d) {
            float df = fq[d] - fn[d];
            s += df * df;
        }
        dj = -sqrtf(s + 1e-6f);
    }
    unsigned long long mb = __ballot(m);
    int cnt = __popcll(mb);
    float mx = wave_max_f32(dj);        // lanes >= NS hold -inf
    float ej = 0.f, pj = 0.f;
    if (lane < NS) {
        ej = expf(dj - mx);             // TEMPERATURE == 1
        pj = m ? ej : 0.f;
    }
    float se = wave_sum_f32(ej);
    float sp = wave_sum_f32(pj);
    bool pm = (cnt > 0) && (cnt < NS);
    if (pm && lane == 0) {
        atomicAdd(pos, (double)sp);
        atomicAdd(neg, (double)se);
        *anyf = 1;
    }
}

__global__ void init_kernel(double* pos, double* neg, int* anyf) {
    int t = threadIdx.x;
    if (t < 5) { pos[t] = 0.0; neg[t] = 0.0; anyf[t] = 0; }
}

__global__ void finalize_kernel(const double* pos, const double* neg,
                                const int* anyf, float* out) {
    if (threadIdx.x == 0 && blockIdx.x == 0) {
        float loss = 0.f;
        for (int i = 0; i < 5; ++i) {
            if (anyf[i]) {
                float p = (float)pos[i];
                float n = (float)neg[i];
                loss += -logf(p / (n + 1e-6f));
            }
        }
        out[0] = loss;
    }
}

extern "C" void kernel_launch(void* const* d_in, const int* in_sizes, int n_in,
                              void* d_out, int out_size, void* d_ws, size_t ws_size,
                              hipStream_t stream) {
    (void)out_size; (void)ws_size;
    const int* labels = (const int*)d_in[0];
    const float* coord[5];
    const float* feat[5];
    bool interleaved = (n_in >= 3 && in_sizes[2] == 2 * 4096 * 32);
    if (interleaved) {
        for (int i = 0; i < 5; ++i) {
            coord[i] = (const float*)d_in[1 + 2 * i];
            feat[i]  = (const float*)d_in[2 + 2 * i];
        }
    } else {
        for (int i = 0; i < 5; ++i) {
            coord[i] = (const float*)d_in[1 + i];
            feat[i]  = (const float*)d_in[6 + i];
        }
    }
    int B = in_sizes[0] / 4096;   // = 2

    double* posA = (double*)d_ws;            // 5 doubles
    double* negA = posA + 5;                 // 5 doubles
    int* anyA = (int*)(negA + 5);            // 5 ints (+3 pad)
    int* lbl1 = anyA + 8;
    int* lbl2 = lbl1 + B * 1024;
    int* lbl3 = lbl2 + B * 256;
    int* lbl4 = lbl3 + B * 64;

    hipLaunchKernelGGL(init_kernel, dim3(1), dim3(64), 0, stream, posA, negA, anyA);

    hipLaunchKernelGGL((knn_label_kernel<4>),  dim3(B * 1024), dim3(64), 0, stream,
                       coord[1], 1024, coord[0], labels, lbl1);
    hipLaunchKernelGGL((knn_label_kernel<8>),  dim3(B * 256),  dim3(64), 0, stream,
                       coord[2], 256,  coord[0], labels, lbl2);
    hipLaunchKernelGGL((knn_label_kernel<12>), dim3(B * 64),   dim3(64), 0, stream,
                       coord[3], 64,   coord[0], labels, lbl3);
    hipLaunchKernelGGL((knn_label_kernel<16>), dim3(B * 16),   dim3(64), 0, stream,
                       coord[4], 16,   coord[0], labels, lbl4);

    hipLaunchKernelGGL((boundary_kernel<4096, 64>), dim3(B * 4096), dim3(64), 0, stream,
                       coord[0], feat[0], labels, posA + 0, negA + 0, anyA + 0);
    hipLaunchKernelGGL((boundary_kernel<1024, 32>), dim3(B * 1024), dim3(64), 0, stream,
                       coord[1], feat[1], lbl1, posA + 1, negA + 1, anyA + 1);
    hipLaunchKernelGGL((boundary_kernel<256, 16>),  dim3(B * 256),  dim3(64), 0, stream,
                       coord[2], feat[2], lbl2, posA + 2, negA + 2, anyA + 2);
    hipLaunchKernelGGL((boundary_kernel<64, 8>),    dim3(B * 64),   dim3(64), 0, stream,
                       coord[3], feat[3], lbl3, posA + 3, negA + 3, anyA + 3);
    hipLaunchKernelGGL((boundary_kernel<16, 4>),    dim3(B * 16),   dim3(64), 0, stream,
                       coord[4], feat[4], lbl4, posA + 4, negA + 4, anyA + 4);

    hipLaunchKernelGGL(finalize_kernel, dim3(1), dim3(1), 0, stream,
                       posA, negA, anyA, (float*)d_out);
}

// Round 4
// 545.193 us; speedup vs baseline: 3.0423x; 1.1387x over previous
//
#include <hip/hip_runtime.h>
#include <math.h>

#define WAVE 64
#define NC 21

__device__ __forceinline__ unsigned f32_ord(float f) {
    unsigned u = __float_as_uint(f);
    return (u & 0x80000000u) ? ~u : (u | 0x80000000u);
}

__device__ __forceinline__ unsigned wave_min_u32(unsigned v) {
#pragma unroll
    for (int off = 32; off >= 1; off >>= 1) {
        unsigned o = __shfl_xor(v, off, WAVE);
        v = (o < v) ? o : v;
    }
    return v;
}

__device__ __forceinline__ int wave_sum_i32(int v) {
#pragma unroll
    for (int off = 32; off >= 1; off >>= 1)
        v += __shfl_xor(v, off, WAVE);
    return v;
}

__device__ __forceinline__ float wave_max_f32(float v) {
#pragma unroll
    for (int off = 32; off >= 1; off >>= 1)
        v = fmaxf(v, __shfl_xor(v, off, WAVE));
    return v;
}

__device__ __forceinline__ float wave_sum_f32(float v) {
#pragma unroll
    for (int off = 32; off >= 1; off >>= 1)
        v += __shfl_xor(v, off, WAVE);
    return v;
}

// ---------------------------------------------------------------------------
// Block-wide exact top-NS *set* selection on ordered-f32 keys.
// BLOCKT threads; each thread owns NPL keys, key ok[j] has global index
// g = j*BLOCKT + tid (0xFFFFFFFF = invalid). Writes the NS selected global
// indices into sel[] (arbitrary order). Tie-break identical to jax.lax.top_k
// (lower global index first). NPL <= 32.
// ---------------------------------------------------------------------------
template <int NPL, int NS, int BLOCKT>
__device__ __forceinline__ void select_knn_set_block(
    const unsigned (&ok)[NPL], int tid, int* sel, int* swave, int* scnt)
{
    constexpr int NW = BLOCKT / WAVE;
    const int lane = tid & 63;
    const int wid = tid >> 6;

    // V = min{v : count(<= v) >= NS}   (uniform binary search, 32 iters)
    unsigned lo = 0u, hi = 0xFFFFFFFFu;
    while (lo < hi) {
        unsigned piv = lo + ((hi - lo) >> 1);
        int c = 0;
#pragma unroll
        for (int j = 0; j < NPL; ++j) c += (ok[j] <= piv) ? 1 : 0;
        c = wave_sum_i32(c);
        int tot;
        if constexpr (NW == 1) {
            tot = c;
        } else {
            if (lane == 0) swave[wid] = c;
            __syncthreads();
            tot = 0;
#pragma unroll
            for (int w = 0; w < NW; ++w) tot += swave[w];
            __syncthreads();
        }
        if (tot >= NS) hi = piv; else lo = piv + 1;
    }
    unsigned V = lo;

    // clt = count(< V)  (uniform)
    int c2 = 0;
#pragma unroll
    for (int j = 0; j < NPL; ++j) c2 += (ok[j] < V) ? 1 : 0;
    c2 = wave_sum_i32(c2);
    int clt;
    if constexpr (NW == 1) {
        clt = c2;
    } else {
        if (lane == 0) swave[wid] = c2;
        __syncthreads();
        clt = 0;
#pragma unroll
        for (int w = 0; w < NW; ++w) clt += swave[w];
        __syncthreads();
    }
    if (tid == 0) *scnt = 0;
    __syncthreads();

    // compact all strictly-below-threshold candidates (ballot prefix within
    // wave, LDS atomic for wave base; order in sel[] is arbitrary — set only)
#pragma unroll
    for (int j = 0; j < NPL; ++j) {
        bool s = ok[j] < V;
        unsigned long long mk = __ballot(s);
        int n = __popcll(mk);
        if (n) {                               // wave-uniform
            int wb = 0;
            if (lane == 0) wb = atomicAdd(scnt, n);
            wb = __shfl(wb, 0, WAVE);
            if (s) sel[wb + __popcll(mk & ((1ull << lane) - 1ull))] =
                       j * BLOCKT + tid;
        }
    }

    // ties at V: take R = NS - clt smallest global indices among ok[j] == V
    int R = NS - clt;                          // uniform, >= 1
    unsigned consumed = 0u;                    // NPL <= 32
    for (int r = 0; r < R; ++r) {
        int bj = NPL;
#pragma unroll
        for (int j = NPL - 1; j >= 0; --j)
            if (ok[j] == V && !((consumed >> j) & 1u)) bj = j;
        unsigned g = (bj < NPL) ? (unsigned)(bj * BLOCKT + tid) : 0xFFFFFFFFu;
        unsigned mg = wave_min_u32(g);
        if constexpr (NW > 1) {
            if (lane == 0) swave[wid] = (int)mg;
            __syncthreads();
            unsigned t = 0xFFFFFFFFu;
#pragma unroll
            for (int w = 0; w < NW; ++w) {
                unsigned x = (unsigned)swave[w];
                t = (x < t) ? x : t;
            }
            __syncthreads();
            mg = t;
        }
        if (bj < NPL && g == mg) {             // unique winner thread
            consumed |= 1u << bj;
            sel[clt + r] = (int)mg;
        }
    }
    __syncthreads();
}

// ---------------------------------------------------------------------------
// Kernel A: for each query in level i (i>0), K nearest in coord0 (4096 pts),
// argmax of neighbor-label counts (lowest class on tie). 256 thr per query.
// ---------------------------------------------------------------------------
template <int K>
__global__ __launch_bounds__(256) void knn_label_kernel(
    const float* __restrict__ qc, int NQ,
    const float* __restrict__ rc,      // [B,4096,3]
    const int* __restrict__ rl,        // [B,4096]
    int* __restrict__ out)             // [B,NQ]
{
    constexpr int BLOCKT = 256;
    constexpr int NPL = 4096 / BLOCKT;         // 16
    __shared__ int sel[K];
    __shared__ int swave[BLOCKT / WAVE];
    __shared__ int scnt;
    int blk = blockIdx.x;
    int b = blk / NQ, qi = blk - b * NQ;
    int tid = threadIdx.x;
    int lane = tid & 63, wid = tid >> 6;

    const float* qp = qc + ((long)b * NQ + qi) * 3;
    float qx = qp[0], qy = qp[1], qz = qp[2];
    float nq = qx * qx + qy * qy + qz * qz;

    const float* rp = rc + (long)b * 4096 * 3;
    unsigned ok[NPL];
#pragma unroll
    for (int j = 0; j < NPL; ++j) {
        int g = j * BLOCKT + tid;
        float rx = rp[3 * g], ry = rp[3 * g + 1], rz = rp[3 * g + 2];
        float nr = rx * rx + ry * ry + rz * rz;
        float dot = qx * rx + qy * ry + qz * rz;
        ok[j] = f32_ord(-2.0f * dot + nq + nr);  // identical expr to R1-R3
    }

    select_knn_set_block<NPL, K, BLOCKT>(ok, tid, sel, swave, &scnt);

    if (wid == 0) {
        int lb = -1;
        if (lane < K) lb = rl[(long)b * 4096 + sel[lane]];
        int cnt = 0;
#pragma unroll
        for (int k = 0; k < K; ++k) {
            int lk = __shfl(lb, k, WAVE);
            cnt += (lk == lane) ? 1 : 0;
        }
        int key = (lane < NC) ? ((cnt << 8) | (255 - lane)) : 0;
#pragma unroll
        for (int off = 32; off >= 1; off >>= 1) {
            int o = __shfl_xor(key, off, WAVE);
            key = (o > key) ? o : key;
        }
        if (lane == 0) out[(long)b * NQ + qi] = 255 - (key & 255);
    }
}

// ---------------------------------------------------------------------------
// Kernel B: per level — KNN set within the level (NS of NI), masked
// feature-softmax accumulation. BLOCKT threads per query; wave 0 finishes.
// ---------------------------------------------------------------------------
template <int NI, int NS, int BLOCKT>
__global__ __launch_bounds__(BLOCKT) void boundary_kernel(
    const float* __restrict__ coord,   // [B,NI,3]
    const float* __restrict__ feat,    // [B,NI,32]
    const int* __restrict__ lbl,       // [B,NI]
    double* __restrict__ pos,
    double* __restrict__ neg,
    int* __restrict__ anyf)
{
    constexpr int NPL = (NI + BLOCKT - 1) / BLOCKT;
    constexpr bool FULL = (NPL * BLOCKT == NI);
    __shared__ int sel[NS];
    __shared__ int swave[BLOCKT / WAVE];
    __shared__ int scnt;
    int blk = blockIdx.x;
    int b = blk / NI, qi = blk - b * NI;
    int tid = threadIdx.x;
    int lane = tid & 63, wid = tid >> 6;

    const float* qp = coord + ((long)b * NI + qi) * 3;
    float qx = qp[0], qy = qp[1], qz = qp[2];
    float nq = qx * qx + qy * qy + qz * qz;

    const float* rp = coord + (long)b * NI * 3;
    unsigned ok[NPL];
#pragma unroll
    for (int j = 0; j < NPL; ++j) {
        int g = j * BLOCKT + tid;
        unsigned o = 0xFFFFFFFFu;
        if (FULL || g < NI) {
            float rx = rp[3 * g], ry = rp[3 * g + 1], rz = rp[3 * g + 2];
            float nr = rx * rx + ry * ry + rz * rz;
            float dot = qx * rx + qy * ry + qz * rz;
            o = f32_ord(-2.0f * dot + nq + nr);
        }
        ok[j] = o;
    }

    select_knn_set_block<NPL, NS, BLOCKT>(ok, tid, sel, swave, &scnt);

    if (wid == 0) {
        int center = lbl[(long)b * NI + qi];
        bool m = false;
        float dj = -INFINITY;
        if (lane < NS) {
            int nb = sel[lane];
            m = (lbl[(long)b * NI + nb] == center);
            const float* fq = feat + ((long)b * NI + qi) * 32;
            const float* fn = feat + ((long)b * NI + nb) * 32;
            float s = 0.f;
#pragma unroll
            for (int d = 0; d < 32; ++d) {
                float df = fq[d] - fn[d];
                s += df * df;
            }
            dj = -sqrtf(s + 1e-6f);
        }
        unsigned long long mb = __ballot(m);
        int cnt = __popcll(mb);
        float mx = wave_max_f32(dj);        // lanes >= NS hold -inf
        float ej = 0.f, pj = 0.f;
        if (lane < NS) {
            ej = expf(dj - mx);             // TEMPERATURE == 1
            pj = m ? ej : 0.f;
        }
        float se = wave_sum_f32(ej);
        float sp = wave_sum_f32(pj);
        bool pm = (cnt > 0) && (cnt < NS);
        if (pm && lane == 0) {
            atomicAdd(pos, (double)sp);
            atomicAdd(neg, (double)se);
            *anyf = 1;
        }
    }
}

__global__ void init_kernel(double* pos, double* neg, int* anyf) {
    int t = threadIdx.x;
    if (t < 5) { pos[t] = 0.0; neg[t] = 0.0; anyf[t] = 0; }
}

__global__ void finalize_kernel(const double* pos, const double* neg,
                                const int* anyf, float* out) {
    if (threadIdx.x == 0 && blockIdx.x == 0) {
        float loss = 0.f;
        for (int i = 0; i < 5; ++i) {
            if (anyf[i]) {
                float p = (float)pos[i];
                float n = (float)neg[i];
                loss += -logf(p / (n + 1e-6f));
            }
        }
        out[0] = loss;
    }
}

extern "C" void kernel_launch(void* const* d_in, const int* in_sizes, int n_in,
                              void* d_out, int out_size, void* d_ws, size_t ws_size,
                              hipStream_t stream) {
    (void)out_size; (void)ws_size;
    const int* labels = (const int*)d_in[0];
    const float* coord[5];
    const float* feat[5];
    bool interleaved = (n_in >= 3 && in_sizes[2] == 2 * 4096 * 32);
    if (interleaved) {
        for (int i = 0; i < 5; ++i) {
            coord[i] = (const float*)d_in[1 + 2 * i];
            feat[i]  = (const float*)d_in[2 + 2 * i];
        }
    } else {
        for (int i = 0; i < 5; ++i) {
            coord[i] = (const float*)d_in[1 + i];
            feat[i]  = (const float*)d_in[6 + i];
        }
    }
    int B = in_sizes[0] / 4096;   // = 2

    double* posA = (double*)d_ws;            // 5 doubles
    double* negA = posA + 5;                 // 5 doubles
    int* anyA = (int*)(negA + 5);            // 5 ints (+3 pad)
    int* lbl1 = anyA + 8;
    int* lbl2 = lbl1 + B * 1024;
    int* lbl3 = lbl2 + B * 256;
    int* lbl4 = lbl3 + B * 64;

    hipLaunchKernelGGL(init_kernel, dim3(1), dim3(64), 0, stream, posA, negA, anyA);

    hipLaunchKernelGGL((knn_label_kernel<4>),  dim3(B * 1024), dim3(256), 0, stream,
                       coord[1], 1024, coord[0], labels, lbl1);
    hipLaunchKernelGGL((knn_label_kernel<8>),  dim3(B * 256),  dim3(256), 0, stream,
                       coord[2], 256,  coord[0], labels, lbl2);
    hipLaunchKernelGGL((knn_label_kernel<12>), dim3(B * 64),   dim3(256), 0, stream,
                       coord[3], 64,   coord[0], labels, lbl3);
    hipLaunchKernelGGL((knn_label_kernel<16>), dim3(B * 16),   dim3(256), 0, stream,
                       coord[4], 16,   coord[0], labels, lbl4);

    hipLaunchKernelGGL((boundary_kernel<4096, 64, 256>), dim3(B * 4096), dim3(256), 0,
                       stream, coord[0], feat[0], labels, posA + 0, negA + 0, anyA + 0);
    hipLaunchKernelGGL((boundary_kernel<1024, 32, 256>), dim3(B * 1024), dim3(256), 0,
                       stream, coord[1], feat[1], lbl1, posA + 1, negA + 1, anyA + 1);
    hipLaunchKernelGGL((boundary_kernel<256, 16, 256>),  dim3(B * 256),  dim3(256), 0,
                       stream, coord[2], feat[2], lbl2, posA + 2, negA + 2, anyA + 2);
    hipLaunchKernelGGL((boundary_kernel<64, 8, 64>),     dim3(B * 64),   dim3(64), 0,
                       stream, coord[3], feat[3], lbl3, posA + 3, negA + 3, anyA + 3);
    hipLaunchKernelGGL((boundary_kernel<16, 4, 64>),     dim3(B * 16),   dim3(64), 0,
                       stream, coord[4], feat[4], lbl4, posA + 4, negA + 4, anyA + 4);

    hipLaunchKernelGGL(finalize_kernel, dim3(1), dim3(1), 0, stream,
                       posA, negA, anyA, (float*)d_out);
}

// Round 5
// 391.610 us; speedup vs baseline: 4.2354x; 1.3922x over previous
//
#include <hip/hip_runtime.h>
#include <math.h>

#define WAVE 64
#define NC 21

__device__ __forceinline__ unsigned f32_ord(float f) {
    unsigned u = __float_as_uint(f);
    return (u & 0x80000000u) ? ~u : (u | 0x80000000u);
}

// Fast wave64 integer sum via DPP (rocPRIM-style row_shr/row_bcast sequence).
// Returns the total, uniform across the wave (readlane 63).
__device__ __forceinline__ int wave_red_sum_dpp(int v) {
    v += __builtin_amdgcn_update_dpp(0, v, 0x111, 0xf, 0xf, true); // row_shr:1
    v += __builtin_amdgcn_update_dpp(0, v, 0x112, 0xf, 0xf, true); // row_shr:2
    v += __builtin_amdgcn_update_dpp(0, v, 0x114, 0xf, 0xf, true); // row_shr:4
    v += __builtin_amdgcn_update_dpp(0, v, 0x118, 0xf, 0xf, true); // row_shr:8
    v += __builtin_amdgcn_update_dpp(0, v, 0x142, 0xa, 0xf, true); // row_bcast:15
    v += __builtin_amdgcn_update_dpp(0, v, 0x143, 0xc, 0xf, true); // row_bcast:31
    return __builtin_amdgcn_readlane(v, 63);
}

__device__ __forceinline__ unsigned wave_min_u32(unsigned v) {
#pragma unroll
    for (int off = 32; off >= 1; off >>= 1) {
        unsigned o = (unsigned)__shfl_xor((int)v, off, WAVE);
        v = (o < v) ? o : v;
    }
    return v;
}

__device__ __forceinline__ unsigned wave_max_u32(unsigned v) {
#pragma unroll
    for (int off = 32; off >= 1; off >>= 1) {
        unsigned o = (unsigned)__shfl_xor((int)v, off, WAVE);
        v = (o > v) ? o : v;
    }
    return v;
}

__device__ __forceinline__ float wave_max_f32(float v) {
#pragma unroll
    for (int off = 32; off >= 1; off >>= 1)
        v = fmaxf(v, __shfl_xor(v, off, WAVE));
    return v;
}

__device__ __forceinline__ float wave_sum_f32(float v) {
#pragma unroll
    for (int off = 32; off >= 1; off >>= 1)
        v += __shfl_xor(v, off, WAVE);
    return v;
}

struct SelShm {
    unsigned long long cand[512];   // 4 wave regions, STRIDE<=128 each
    int wcnt[4];
    int sel[64];
};

// ---------------------------------------------------------------------------
// Block-wide exact top-NS set selection of nearest neighbors.
// 256 threads = 4 waves; wave w owns slice [w*NI/4, (w+1)*NI/4).
// Phase 1 (wave-local, barrier-free): adaptive binary search narrows the
// slice to <= NS-1+CAPX candidates, compacted to LDS as (key<<32|g).
// Phase 2 (wave 0): exact top-NS over <= 4*STRIDE candidates; ties broken by
// lowest global index (matches jax.lax.top_k). Result in shm.sel[0..NS).
// Exactly ONE __syncthreads per call.
// ---------------------------------------------------------------------------
template <int NI, int NS>
__device__ __forceinline__ void block_select_topNS(
    const float* __restrict__ rp,   // [NI,3] coords for this batch
    float qx, float qy, float qz, float nq,
    SelShm& shm, int tid)
{
    constexpr int SLICE = NI / 4;
    constexpr int NPL = (SLICE >= 64) ? (SLICE / 64) : 1;
    constexpr int CAPX = (NS < 32) ? 32 : NS;
    constexpr int STRIDE = NS + CAPX;           // <= 128
    const int lane = tid & 63;
    const int wid = tid >> 6;
    const int wbase = wid * SLICE;
    const unsigned long long lmask = (1ull << lane) - 1ull;

    unsigned ok[NPL];
#pragma unroll
    for (int j = 0; j < NPL; ++j) {
        unsigned o = 0xFFFFFFFFu;
        int gl = (SLICE >= 64) ? (j * 64 + lane) : lane;
        if (SLICE >= 64 || lane < SLICE) {
            int g = wbase + gl;
            float rx = rp[3*g], ry = rp[3*g+1], rz = rp[3*g+2];
            float nr = rx*rx + ry*ry + rz*rz;
            float dot = qx*rx + qy*ry + qz*rz;
            o = f32_ord(-2.0f*dot + nq + nr);   // identical expr to R1-R4
        }
        ok[j] = o;
    }

    // seed [lo,hi] with the slice's key range
    unsigned mn = 0xFFFFFFFFu, mx = 0u;
#pragma unroll
    for (int j = 0; j < NPL; ++j) {
        mn = (ok[j] < mn) ? ok[j] : mn;
        unsigned v = (ok[j] == 0xFFFFFFFFu) ? 0u : ok[j];
        mx = (v > mx) ? v : mx;
    }
    mn = wave_min_u32(mn);
    mx = wave_max_u32(mx);

    unsigned lo = mn, hi = mx;
    int cLo = 0, cHi = SLICE;                   // cnt(<lo), cnt(<=hi)
    while (lo < hi && (cHi - cLo) > CAPX) {
        unsigned piv = lo + ((hi - lo) >> 1);
        int c = 0;
#pragma unroll
        for (int j = 0; j < NPL; ++j) c += (ok[j] <= piv) ? 1 : 0;
        c = wave_red_sum_dpp(c);
        if (c >= NS) { hi = piv; cHi = c; } else { lo = piv + 1; cLo = c; }
    }

    unsigned long long* cw = shm.cand + wid * STRIDE;
    int wcnt;
    if (lo == hi && (cHi - cLo) > CAPX) {
        // degenerate tie mass at V=lo: emit keys<V plus (NS-cLo) smallest-g ties
        unsigned V = lo;
        int off = 0;
#pragma unroll
        for (int j = 0; j < NPL; ++j) {
            bool s = ok[j] < V;
            unsigned long long mk = __ballot(s);
            if (s) {
                int gl = (SLICE >= 64) ? (j*64 + lane) : lane;
                cw[off + __popcll(mk & lmask)] =
                    ((unsigned long long)ok[j] << 32) | (unsigned)(wbase + gl);
            }
            off += __popcll(mk);
        }
        int R = NS - off;                       // off == cLo
        unsigned consumed = 0u;
        for (int r = 0; r < R; ++r) {
            int bj = -1;
#pragma unroll
            for (int j = NPL - 1; j >= 0; --j)
                if (ok[j] == V && !((consumed >> j) & 1u)) bj = j;
            unsigned g = 0xFFFFFFFFu;
            if (bj >= 0) {
                int gl = (SLICE >= 64) ? (bj*64 + lane) : lane;
                g = (unsigned)(wbase + gl);
            }
            unsigned mg = wave_min_u32(g);
            if (bj >= 0 && g == mg) consumed |= (1u << bj);
            if (lane == 0) cw[off + r] = ((unsigned long long)V << 32) | mg;
        }
        wcnt = NS;
    } else {
        // survivors = all keys <= hi; count = cHi <= NS-1+CAPX <= STRIDE
        int off = 0;
#pragma unroll
        for (int j = 0; j < NPL; ++j) {
            bool s = ok[j] <= hi;
            unsigned long long mk = __ballot(s);
            if (s) {
                int gl = (SLICE >= 64) ? (j*64 + lane) : lane;
                cw[off + __popcll(mk & lmask)] =
                    ((unsigned long long)ok[j] << 32) | (unsigned)(wbase + gl);
            }
            off += __popcll(mk);
        }
        wcnt = off;
    }
    if (lane == 0) shm.wcnt[wid] = wcnt;
    __syncthreads();

    if (wid == 0) {
        constexpr int CAND = 4 * STRIDE;
        constexpr int NPLC = (CAND + 63) / 64;
        unsigned long long ck[NPLC];
        int w0 = shm.wcnt[0], w1 = shm.wcnt[1], w2 = shm.wcnt[2], w3 = shm.wcnt[3];
#pragma unroll
        for (int i = 0; i < NPLC; ++i) {
            int idx = i * 64 + lane;
            unsigned long long v = ~0ull;
            if (idx < CAND) {
                int w = idx / STRIDE;
                int slot = idx - w * STRIDE;
                int wc = (w == 0) ? w0 : (w == 1) ? w1 : (w == 2) ? w2 : w3;
                if (slot < wc) v = shm.cand[idx];
            }
            ck[i] = v;
        }
        unsigned mn2 = 0xFFFFFFFFu, mx2 = 0u;
#pragma unroll
        for (int i = 0; i < NPLC; ++i) {
            unsigned k = (unsigned)(ck[i] >> 32);
            mn2 = (k < mn2) ? k : mn2;
            unsigned v = (k == 0xFFFFFFFFu) ? 0u : k;
            mx2 = (v > mx2) ? v : mx2;
        }
        mn2 = wave_min_u32(mn2);
        mx2 = wave_max_u32(mx2);
        unsigned lo2 = mn2, hi2 = mx2;
        while (lo2 < hi2) {
            unsigned piv = lo2 + ((hi2 - lo2) >> 1);
            int c = 0;
#pragma unroll
            for (int i = 0; i < NPLC; ++i)
                c += ((unsigned)(ck[i] >> 32) <= piv) ? 1 : 0;
            c = wave_red_sum_dpp(c);
            if (c >= NS) hi2 = piv; else lo2 = piv + 1;
        }
        unsigned V2 = lo2;
        int c2 = 0;
#pragma unroll
        for (int i = 0; i < NPLC; ++i)
            c2 += ((unsigned)(ck[i] >> 32) < V2) ? 1 : 0;
        int clt2 = wave_red_sum_dpp(c2);
        int R2 = NS - clt2;
        int off = 0;
#pragma unroll
        for (int i = 0; i < NPLC; ++i) {
            bool s = ((unsigned)(ck[i] >> 32)) < V2;
            unsigned long long mk = __ballot(s);
            if (s) shm.sel[off + __popcll(mk & lmask)] = (int)(unsigned)ck[i];
            off += __popcll(mk);
        }
        unsigned consumed = 0u;
        for (int r = 0; r < R2; ++r) {
            unsigned bg = 0xFFFFFFFFu; int bi = -1;
#pragma unroll
            for (int i = 0; i < NPLC; ++i) {
                unsigned k = (unsigned)(ck[i] >> 32);
                unsigned g = (unsigned)ck[i];
                if (k == V2 && !((consumed >> i) & 1u) && g < bg) { bg = g; bi = i; }
            }
            unsigned mg = wave_min_u32(bg);
            if (bi >= 0 && bg == mg) consumed |= (1u << bi);
            if (lane == 0) shm.sel[clt2 + r] = (int)mg;
        }
    }
    // no trailing barrier: only wave 0 consumes shm.sel
}

// ---------------------------------------------------------------------------
template <int NQ, int K>
__device__ __forceinline__ void knn_level(
    const float* __restrict__ qc, const float* __restrict__ rc,
    const int* __restrict__ rl, int* __restrict__ out,
    int qb, SelShm& shm, int tid)
{
    int b = qb / NQ, qi = qb - b * NQ;
    const float* qp = qc + ((long)b * NQ + qi) * 3;
    float qx = qp[0], qy = qp[1], qz = qp[2];
    float nq = qx*qx + qy*qy + qz*qz;
    block_select_topNS<4096, K>(rc + (long)b * 4096 * 3, qx, qy, qz, nq, shm, tid);
    if ((tid >> 6) == 0) {
        int lane = tid & 63;
        int lb = (lane < K) ? rl[(long)b * 4096 + shm.sel[lane]] : -1;
        int cnt = 0;
#pragma unroll
        for (int k = 0; k < K; ++k) {
            int lk = __shfl(lb, k, WAVE);
            cnt += (lk == lane) ? 1 : 0;
        }
        int key = (lane < NC) ? ((cnt << 8) | (255 - lane)) : 0;
#pragma unroll
        for (int off = 32; off >= 1; off >>= 1) {
            int o = __shfl_xor(key, off, WAVE);
            key = (o > key) ? o : key;
        }
        if (lane == 0) out[(long)b * NQ + qi] = 255 - (key & 255);
    }
}

template <int NI, int NS>
__device__ __forceinline__ void boundary_level(
    const float* __restrict__ coord, const float* __restrict__ feat,
    const int* __restrict__ lbl,
    double* __restrict__ pos, double* __restrict__ neg, int* __restrict__ anyf,
    int qb, SelShm& shm, int tid)
{
    int b = qb / NI, qi = qb - b * NI;
    const float* qp = coord + ((long)b * NI + qi) * 3;
    float qx = qp[0], qy = qp[1], qz = qp[2];
    float nq = qx*qx + qy*qy + qz*qz;
    block_select_topNS<NI, NS>(coord + (long)b * NI * 3, qx, qy, qz, nq, shm, tid);
    if ((tid >> 6) == 0) {
        int lane = tid & 63;
        int center = lbl[(long)b * NI + qi];
        bool m = false;
        float dj = -INFINITY;
        if (lane < NS) {
            int nb = shm.sel[lane];
            m = (lbl[(long)b * NI + nb] == center);
            const float4* fq = (const float4*)(feat + ((long)b * NI + qi) * 32);
            const float4* fn = (const float4*)(feat + ((long)b * NI + nb) * 32);
            float s = 0.f;
#pragma unroll
            for (int d = 0; d < 8; ++d) {
                float4 a = fq[d], c = fn[d];
                float d0 = a.x - c.x, d1 = a.y - c.y;
                float d2 = a.z - c.z, d3 = a.w - c.w;
                s += d0*d0 + d1*d1 + d2*d2 + d3*d3;
            }
            dj = -sqrtf(s + 1e-6f);
        }
        unsigned long long mb = __ballot(m);
        int cnt = __popcll(mb);
        float mxv = wave_max_f32(dj);          // lanes >= NS hold -inf
        float ej = 0.f, pj = 0.f;
        if (lane < NS) {
            ej = expf(dj - mxv);               // TEMPERATURE == 1
            pj = m ? ej : 0.f;
        }
        float se = wave_sum_f32(ej);
        float sp = wave_sum_f32(pj);
        bool pm = (cnt > 0) && (cnt < NS);
        if (pm && lane == 0) {
            atomicAdd(pos, (double)sp);
            atomicAdd(neg, (double)se);
            *anyf = 1;
        }
    }
}

// ---------------------------------------------------------------------------
__global__ __launch_bounds__(256) void knn_fused(
    const float* __restrict__ c1, const float* __restrict__ c2,
    const float* __restrict__ c3, const float* __restrict__ c4,
    const float* __restrict__ c0, const int* __restrict__ labels,
    int* __restrict__ lbl1, int* __restrict__ lbl2,
    int* __restrict__ lbl3, int* __restrict__ lbl4,
    double* __restrict__ posA, double* __restrict__ negA,
    int* __restrict__ anyA, int B)
{
    __shared__ SelShm shm;
    int blk = blockIdx.x, tid = threadIdx.x;
    int n1 = B * 1024, n2 = n1 + B * 256, n3 = n2 + B * 64, n4 = n3 + B * 16;
    if (blk < n1)      knn_level<1024, 4>(c1, c0, labels, lbl1, blk,      shm, tid);
    else if (blk < n2) knn_level<256,  8>(c2, c0, labels, lbl2, blk - n1, shm, tid);
    else if (blk < n3) knn_level<64,  12>(c3, c0, labels, lbl3, blk - n2, shm, tid);
    else if (blk < n4) knn_level<16,  16>(c4, c0, labels, lbl4, blk - n3, shm, tid);
    else if (tid < 5) { posA[tid] = 0.0; negA[tid] = 0.0; anyA[tid] = 0; }
}

__global__ __launch_bounds__(256) void boundary_fused(
    const float* __restrict__ c0, const float* __restrict__ c1,
    const float* __restrict__ c2, const float* __restrict__ c3,
    const float* __restrict__ c4,
    const float* __restrict__ f0, const float* __restrict__ f1,
    const float* __restrict__ f2, const float* __restrict__ f3,
    const float* __restrict__ f4,
    const int* __restrict__ labels, const int* __restrict__ lbl1,
    const int* __restrict__ lbl2, const int* __restrict__ lbl3,
    const int* __restrict__ lbl4,
    double* __restrict__ posA, double* __restrict__ negA,
    int* __restrict__ anyA, int B)
{
    __shared__ SelShm shm;
    int blk = blockIdx.x, tid = threadIdx.x;
    int m0 = B * 4096, m1 = m0 + B * 1024, m2 = m1 + B * 256;
    int m3 = m2 + B * 64, m4 = m3 + B * 16;
    if (blk < m0)
        boundary_level<4096, 64>(c0, f0, labels, posA+0, negA+0, anyA+0, blk,      shm, tid);
    else if (blk < m1)
        boundary_level<1024, 32>(c1, f1, lbl1,   posA+1, negA+1, anyA+1, blk - m0, shm, tid);
    else if (blk < m2)
        boundary_level<256,  16>(c2, f2, lbl2,   posA+2, negA+2, anyA+2, blk - m1, shm, tid);
    else if (blk < m3)
        boundary_level<64,    8>(c3, f3, lbl3,   posA+3, negA+3, anyA+3, blk - m2, shm, tid);
    else if (blk < m4)
        boundary_level<16,    4>(c4, f4, lbl4,   posA+4, negA+4, anyA+4, blk - m3, shm, tid);
}

__global__ void finalize_kernel(const double* __restrict__ pos,
                                const double* __restrict__ neg,
                                const int* __restrict__ anyf,
                                float* __restrict__ out) {
    if (threadIdx.x == 0 && blockIdx.x == 0) {
        float loss = 0.f;
        for (int i = 0; i < 5; ++i) {
            if (anyf[i]) {
                float p = (float)pos[i];
                float n = (float)neg[i];
                loss += -logf(p / (n + 1e-6f));
            }
        }
        out[0] = loss;
    }
}

extern "C" void kernel_launch(void* const* d_in, const int* in_sizes, int n_in,
                              void* d_out, int out_size, void* d_ws, size_t ws_size,
                              hipStream_t stream) {
    (void)out_size; (void)ws_size;
    const int* labels = (const int*)d_in[0];
    const float* coord[5];
    const float* feat[5];
    bool interleaved = (n_in >= 3 && in_sizes[2] == 2 * 4096 * 32);
    if (interleaved) {
        for (int i = 0; i < 5; ++i) {
            coord[i] = (const float*)d_in[1 + 2 * i];
            feat[i]  = (const float*)d_in[2 + 2 * i];
        }
    } else {
        for (int i = 0; i < 5; ++i) {
            coord[i] = (const float*)d_in[1 + i];
            feat[i]  = (const float*)d_in[6 + i];
        }
    }
    int B = in_sizes[0] / 4096;   // = 2

    double* posA = (double*)d_ws;            // 5 doubles
    double* negA = posA + 5;                 // 5 doubles
    int* anyA = (int*)(negA + 5);            // 5 ints (+3 pad)
    int* lbl1 = anyA + 8;
    int* lbl2 = lbl1 + B * 1024;
    int* lbl3 = lbl2 + B * 256;
    int* lbl4 = lbl3 + B * 64;

    int knn_grid = B * (1024 + 256 + 64 + 16) + 1;     // +1 block does init
    hipLaunchKernelGGL(knn_fused, dim3(knn_grid), dim3(256), 0, stream,
                       coord[1], coord[2], coord[3], coord[4],
                       coord[0], labels, lbl1, lbl2, lbl3, lbl4,
                       posA, negA, anyA, B);

    int bnd_grid = B * (4096 + 1024 + 256 + 64 + 16);
    hipLaunchKernelGGL(boundary_fused, dim3(bnd_grid), dim3(256), 0, stream,
                       coord[0], coord[1], coord[2], coord[3], coord[4],
                       feat[0], feat[1], feat[2], feat[3], feat[4],
                       labels, lbl1, lbl2, lbl3, lbl4,
                       posA, negA, anyA, B);

    hipLaunchKernelGGL(finalize_kernel, dim3(1), dim3(1), 0, stream,
                       posA, negA, anyA, (float*)d_out);
}